// Round 3
// baseline (394.607 us; speedup 1.0000x reference)
//
#include <hip/hip_runtime.h>
#include <math.h>

// B=8, N=1024, DIM=768, H=12, dh=64 -> M=8192, EQKV=2304
// Split-precision bf16: x ~= hi + lo; 3-MFMA emulated fp32 GEMM (2-term for PV).
// Planar H/L operands everywhere so GEMMs stage via global_load_lds (no VALU).

typedef __attribute__((ext_vector_type(8))) short short8;
typedef __attribute__((ext_vector_type(4))) float f32x4;

#define MFMA(a, b, c) __builtin_amdgcn_mfma_f32_16x16x32_bf16((a), (b), (c), 0, 0, 0)

// global -> LDS direct DMA, 16B per lane. LDS dest must be wave-uniform base.
#define GLDS16(gp, lp) \
  __builtin_amdgcn_global_load_lds((__attribute__((address_space(1))) const void*)(gp), \
                                   (__attribute__((address_space(3))) void*)(lp), 16, 0, 0)

__device__ __forceinline__ unsigned short f2bf(float x) {
  unsigned u = __builtin_bit_cast(unsigned, x);
  return (unsigned short)((u + 0x7FFFu + ((u >> 16) & 1u)) >> 16);
}
__device__ __forceinline__ float bf2f(unsigned short h) {
  unsigned u = ((unsigned)h) << 16;
  return __builtin_bit_cast(float, u);
}

// ---------------------------------------------------------------------------
// fp32 -> planar (hi, lo) bf16 split. 8 elements / thread.
// ---------------------------------------------------------------------------
__global__ __launch_bounds__(256)
void k_split(const float* __restrict__ x, short* __restrict__ h,
             short* __restrict__ l, int n8)
{
  const int i = blockIdx.x * 256 + threadIdx.x;
  if (i >= n8) return;
  float4 a = ((const float4*)x)[2 * i];
  float4 b = ((const float4*)x)[2 * i + 1];
  float v[8] = {a.x, a.y, a.z, a.w, b.x, b.y, b.z, b.w};
  short8 hh, ll;
#pragma unroll
  for (int e = 0; e < 8; ++e) {
    unsigned short hi = f2bf(v[e]);
    hh[e] = (short)hi;
    ll[e] = (short)f2bf(v[e] - bf2f(hi));
  }
  ((short8*)h)[i] = hh;
  ((short8*)l)[i] = ll;
}

// ---------------------------------------------------------------------------
// C[M x Ndim] = (AH+AL)[M x K] * (WH+WL)[Ndim x K]^T (+bias), 3-term MFMA.
// 128x128 tile, BK=32, 256 thr (4 waves, 2x2 of 64x64), global_load_lds stage.
// ---------------------------------------------------------------------------
template <bool STORE_PACKED, bool BIAS>
__global__ __launch_bounds__(256, 3)
void k_gemm(const short* __restrict__ AH, const short* __restrict__ AL,
            const short* __restrict__ WH, const short* __restrict__ WL,
            const float* __restrict__ bias, void* __restrict__ Cvoid,
            int Ndim, int K)
{
  __shared__ __align__(16) short As[2][128][32];   // [H/L][row][k]
  __shared__ __align__(16) short Ws[2][128][32];   // 32 KiB total

  const int tid = threadIdx.x, lane = tid & 63, w = tid >> 6;
  const int wm = w >> 1, wn = w & 1;
  const int fr = lane & 15, fk = (lane >> 4) * 8;
  const int bm = blockIdx.x * 128, bn = blockIdx.y * 128;

  const int srow = lane >> 2;        // 0..15 (4 lanes per row: 4 x 16B = 64B row)
  const int scol = (lane & 3) * 8;   // shorts

  f32x4 acc[4][4];
#pragma unroll
  for (int i = 0; i < 4; ++i)
#pragma unroll
    for (int j = 0; j < 4; ++j) acc[i][j] = (f32x4){0.f, 0.f, 0.f, 0.f};

  const int nk = K >> 5;
  for (int kt = 0; kt < nk; ++kt) {
    const int k0 = kt << 5;
    __syncthreads();                 // prev compute done reading LDS
#pragma unroll
    for (int j = 0; j < 2; ++j) {
      const int rb = j * 64 + w * 16;          // wave-uniform row base
      const size_t aoff = (size_t)(bm + rb + srow) * K + k0 + scol;
      const size_t woff = (size_t)(bn + rb + srow) * K + k0 + scol;
      GLDS16(AH + aoff, &As[0][rb][0]);
      GLDS16(AL + aoff, &As[1][rb][0]);
      GLDS16(WH + woff, &Ws[0][rb][0]);
      GLDS16(WL + woff, &Ws[1][rb][0]);
    }
    __syncthreads();                 // compiler drains vmcnt before barrier

    short8 aH[4], aL[4], bH[4], bL[4];
#pragma unroll
    for (int i = 0; i < 4; ++i) {
      aH[i] = *(const short8*)&As[0][wm * 64 + i * 16 + fr][fk];
      aL[i] = *(const short8*)&As[1][wm * 64 + i * 16 + fr][fk];
      bH[i] = *(const short8*)&Ws[0][wn * 64 + i * 16 + fr][fk];
      bL[i] = *(const short8*)&Ws[1][wn * 64 + i * 16 + fr][fk];
    }
#pragma unroll
    for (int i = 0; i < 4; ++i)
#pragma unroll
      for (int j = 0; j < 4; ++j) {
        acc[i][j] = MFMA(aH[i], bH[j], acc[i][j]);
        acc[i][j] = MFMA(aH[i], bL[j], acc[i][j]);
        acc[i][j] = MFMA(aL[i], bH[j], acc[i][j]);
      }
  }

  // ---- epilogue (D-layout: col=lane&15, row=(lane>>4)*4+r) ----
  const int row0 = bm + wm * 64 + (lane >> 4) * 4;
  const int col0 = bn + wn * 64 + fr;
  if constexpr (STORE_PACKED) {
    unsigned* Cp = (unsigned*)Cvoid;
#pragma unroll
    for (int i = 0; i < 4; ++i)
#pragma unroll
      for (int j = 0; j < 4; ++j) {
        const int row = row0 + i * 16, col = col0 + j * 16;
#pragma unroll
        for (int r = 0; r < 4; ++r) {
          float x = acc[i][j][r];
          unsigned short hi = f2bf(x);
          unsigned short lo = f2bf(x - bf2f(hi));
          Cp[(size_t)(row + r) * Ndim + col] = (((unsigned)hi) << 16) | lo;
        }
      }
  } else {
    float* Cp = (float*)Cvoid;
    float bj[4] = {0.f, 0.f, 0.f, 0.f};
    if constexpr (BIAS) {
#pragma unroll
      for (int j = 0; j < 4; ++j) bj[j] = bias[col0 + j * 16];
    }
#pragma unroll
    for (int i = 0; i < 4; ++i)
#pragma unroll
      for (int j = 0; j < 4; ++j) {
        const int row = row0 + i * 16, col = col0 + j * 16;
#pragma unroll
        for (int r = 0; r < 4; ++r)
          Cp[(size_t)(row + r) * Ndim + col] = acc[i][j][r] + bj[j];
      }
  }
}

// ---------------------------------------------------------------------------
// Flash attention. Block = 512 thr (8 waves), q-tile 128 (16 rows/wave),
// KV tiles of 64. qkvP packed u32 (hi|lo). scores = 8*(q.k).
// QK^T: 3-term split. PV: 2-term (Ph*Vh + Ph*Vl). Output planar H/L bf16.
// LDS 53248 B -> 3 blocks/CU (grid 768 = 256*3, single dispatch round).
// ---------------------------------------------------------------------------
__global__ __launch_bounds__(512, 6)
void k_attn(const unsigned* __restrict__ qkvP,
            short* __restrict__ attH, short* __restrict__ attL)
{
  __shared__ __align__(16) short KsH[64][72];
  __shared__ __align__(16) short KsL[64][72];
  __shared__ __align__(16) short VtH[64][72];
  __shared__ __align__(16) short VtL[64][72];
  __shared__ __align__(16) short Ps[8][16][64];

  const int tid = threadIdx.x, lane = tid & 63, w = tid >> 6;
  const int fr = lane & 15, fk = (lane >> 4) * 8;
  const int q4 = lane >> 4;

  // XCD-swizzled decode: all 8 q-tiles of a head land on one XCD.
  const int bid = blockIdx.x;
  const int lg = (bid & 7) * 96 + (bid >> 3);
  const int qt = lg & 7;          // 0..7 (128-row q tile)
  const int bh = lg >> 3;         // 0..95
  const int b = bh / 12, h = bh - b * 12;
  const unsigned* base = qkvP + (size_t)b * 1024 * 2304 + (size_t)h * 192;

  // Q fragments in registers across all KV tiles
  short8 qH[2], qL[2];
  {
    const unsigned* qp = base + (size_t)(qt * 128 + w * 16 + fr) * 2304;
#pragma unroll
    for (int ks = 0; ks < 2; ++ks) {
      uint4 u0 = *(const uint4*)(qp + 32 * ks + fk);
      uint4 u1 = *(const uint4*)(qp + 32 * ks + fk + 4);
      unsigned uu[8] = {u0.x, u0.y, u0.z, u0.w, u1.x, u1.y, u1.z, u1.w};
#pragma unroll
      for (int e = 0; e < 8; ++e) {
        qH[ks][e] = (short)(uu[e] >> 16);
        qL[ks][e] = (short)(uu[e] & 0xffffu);
      }
    }
  }

  f32x4 O[4];
  float mrun[4], lrun[4];
#pragma unroll
  for (int r = 0; r < 4; ++r) { mrun[r] = -INFINITY; lrun[r] = 0.f; }
#pragma unroll
  for (int nf = 0; nf < 4; ++nf) O[nf] = (f32x4){0.f, 0.f, 0.f, 0.f};

  const int skv = tid & 63;
  const int sd  = (tid >> 6) * 8;
  const unsigned* kvbase = base + 64 + sd;

  for (int kt = 0; kt < 16; ++kt) {
    __syncthreads();
    {   // stage K row-major + V transposed, hi/lo
      const unsigned* kp = kvbase + (size_t)(kt * 64 + skv) * 2304;
      uint4 ku0 = *(const uint4*)(kp);
      uint4 ku1 = *(const uint4*)(kp + 4);
      uint4 vu0 = *(const uint4*)(kp + 64);
      uint4 vu1 = *(const uint4*)(kp + 68);
      unsigned ka[8] = {ku0.x, ku0.y, ku0.z, ku0.w, ku1.x, ku1.y, ku1.z, ku1.w};
      short8 kh, kl;
#pragma unroll
      for (int e = 0; e < 8; ++e) { kh[e] = (short)(ka[e] >> 16); kl[e] = (short)(ka[e] & 0xffffu); }
      *(short8*)&KsH[skv][sd] = kh;
      *(short8*)&KsL[skv][sd] = kl;
      unsigned va[8] = {vu0.x, vu0.y, vu0.z, vu0.w, vu1.x, vu1.y, vu1.z, vu1.w};
#pragma unroll
      for (int e = 0; e < 8; ++e) {
        VtH[sd + e][skv] = (short)(va[e] >> 16);
        VtL[sd + e][skv] = (short)(va[e] & 0xffffu);
      }
    }
    __syncthreads();

    // S = 8 * Q K^T (3-term)
    f32x4 S[4];
#pragma unroll
    for (int nf = 0; nf < 4; ++nf) S[nf] = (f32x4){0.f, 0.f, 0.f, 0.f};
#pragma unroll
    for (int ks = 0; ks < 2; ++ks)
#pragma unroll
      for (int nf = 0; nf < 4; ++nf) {
        short8 kbh = *(const short8*)&KsH[nf * 16 + fr][fk + 32 * ks];
        short8 kbl = *(const short8*)&KsL[nf * 16 + fr][fk + 32 * ks];
        S[nf] = MFMA(qH[ks], kbh, S[nf]);
        S[nf] = MFMA(qH[ks], kbl, S[nf]);
        S[nf] = MFMA(qL[ks], kbh, S[nf]);
      }

    // online softmax (rows in D-layout: row=(lane>>4)*4+r)
    float tmax[4];
#pragma unroll
    for (int r = 0; r < 4; ++r) {
      float a = S[0][r] * 8.f, b2 = S[1][r] * 8.f, c = S[2][r] * 8.f, d = S[3][r] * 8.f;
      S[0][r] = a; S[1][r] = b2; S[2][r] = c; S[3][r] = d;
      tmax[r] = fmaxf(fmaxf(a, b2), fmaxf(c, d));
    }
#pragma unroll
    for (int off = 1; off < 16; off <<= 1)
#pragma unroll
      for (int r = 0; r < 4; ++r) tmax[r] = fmaxf(tmax[r], __shfl_xor(tmax[r], off));

    float Pv[4][4], rsum[4], al[4];
#pragma unroll
    for (int r = 0; r < 4; ++r) {
      float mn = fmaxf(mrun[r], tmax[r]);
      al[r] = __expf(mrun[r] - mn);
      mrun[r] = mn;
      rsum[r] = 0.f;
#pragma unroll
      for (int nf = 0; nf < 4; ++nf) {
        float p = __expf(S[nf][r] - mn);
        Pv[nf][r] = p;
        rsum[r] += p;
      }
    }
#pragma unroll
    for (int off = 1; off < 16; off <<= 1)
#pragma unroll
      for (int r = 0; r < 4; ++r) rsum[r] += __shfl_xor(rsum[r], off);
#pragma unroll
    for (int r = 0; r < 4; ++r) lrun[r] = lrun[r] * al[r] + rsum[r];
#pragma unroll
    for (int nf = 0; nf < 4; ++nf)
#pragma unroll
      for (int r = 0; r < 4; ++r) O[nf][r] *= al[r];

    // P(hi) -> per-wave LDS; nf staggered per quarter-wave (bank spread)
    const int pr = q4 * 4;
#pragma unroll
    for (int nn = 0; nn < 4; ++nn) {
      const int nf = (nn + q4) & 3;
#pragma unroll
      for (int r = 0; r < 4; ++r)
        Ps[w][pr + r][nf * 16 + fr] = (short)f2bf(Pv[nf][r]);
    }

    // O += P V (2-term: Ph*Vh + Ph*Vl)
#pragma unroll
    for (int ks = 0; ks < 2; ++ks) {
      short8 paH = *(const short8*)&Ps[w][fr][fk + 32 * ks];
#pragma unroll
      for (int nf = 0; nf < 4; ++nf) {
        short8 vbH = *(const short8*)&VtH[nf * 16 + fr][fk + 32 * ks];
        short8 vbL = *(const short8*)&VtL[nf * 16 + fr][fk + 32 * ks];
        O[nf] = MFMA(paH, vbH, O[nf]);
        O[nf] = MFMA(paH, vbL, O[nf]);
      }
    }
  }

  // normalize + planar H/L store, merged heads [B*N][768]
  {
    const size_t rowbase = (size_t)(b * 1024 + qt * 128 + w * 16 + q4 * 4);
#pragma unroll
    for (int r = 0; r < 4; ++r) {
      const float inv = 1.f / lrun[r];
#pragma unroll
      for (int nf = 0; nf < 4; ++nf) {
        const float v = O[nf][r] * inv;
        const size_t idx = (rowbase + r) * 768 + h * 64 + nf * 16 + fr;
        unsigned short hi = f2bf(v);
        attH[idx] = (short)hi;
        attL[idx] = (short)f2bf(v - bf2f(hi));
      }
    }
  }
}

// ---------------------------------------------------------------------------

extern "C" void kernel_launch(void* const* d_in, const int* in_sizes, int n_in,
                              void* d_out, int out_size, void* d_ws, size_t ws_size,
                              hipStream_t stream)
{
  const float* img  = (const float*)d_in[0];   // [8,1024,768]
  const float* Wqkv = (const float*)d_in[1];   // [2304,768]
  const float* Wfc  = (const float*)d_in[2];   // [768,768]
  const float* bfc  = (const float*)d_in[3];   // [768]
  float* outp = (float*)d_out;                 // [8,1024,768] fp32

  char* ws = (char*)d_ws;
  unsigned* qkvP = (unsigned*)ws;                       // 75,497,472 B
  short* imgH  = (short*)(ws + 75497472);               // 12,582,912
  short* imgL  = (short*)(ws + 88080384);               // 12,582,912
  short* WqkvH = (short*)(ws + 100663296);              //  3,538,944
  short* WqkvL = (short*)(ws + 104202240);              //  3,538,944
  short* WfcH  = (short*)(ws + 107741184);              //  1,179,648
  short* WfcL  = (short*)(ws + 108920832);              //  1,179,648  (end 110.1 MB)
  short* attH  = imgH;                                  // alias: img dead after gemm1
  short* attL  = imgL;

  // 0) fp32 -> planar hi/lo bf16
  k_split<<<3072, 256, 0, stream>>>(img,  imgH,  imgL,  786432);
  k_split<<<864,  256, 0, stream>>>(Wqkv, WqkvH, WqkvL, 221184);
  k_split<<<288,  256, 0, stream>>>(Wfc,  WfcH,  WfcL,  73728);
  // 1) qkv = img @ Wqkv^T  (planar in, packed u32 out)
  k_gemm<true, false><<<dim3(64, 18), dim3(256), 0, stream>>>(
      imgH, imgL, WqkvH, WqkvL, nullptr, (void*)qkvP, 2304, 768);
  // 2) flash attention (packed in, planar out)
  k_attn<<<dim3(768), dim3(512), 0, stream>>>(qkvP, attH, attL);
  // 3) out = att @ Wfc^T + b  (planar in, fp32 out)
  k_gemm<false, true><<<dim3(64, 6), dim3(256), 0, stream>>>(
      attH, attL, WfcH, WfcL, bfc, (void*)outp, 768, 768);
}

// Round 8
// 304.589 us; speedup vs baseline: 1.2955x; 1.2955x over previous
//
#include <hip/hip_runtime.h>
#include <math.h>

// B=8, N=1024, DIM=768, H=12, dh=64 -> M=8192, EQKV=2304
// Split-precision bf16: x ~= hi + lo. 3-term MFMA GEMMs, 3-term QK, 2-term PV.
// All GEMM/attn staging via global_load_lds with XOR-swizzled sources (T2/m173).

typedef __attribute__((ext_vector_type(8))) short short8;
typedef __attribute__((ext_vector_type(4))) float f32x4;

#define MFMA(a, b, c) __builtin_amdgcn_mfma_f32_16x16x32_bf16((a), (b), (c), 0, 0, 0)

#define GLDS16(gp, lp) \
  __builtin_amdgcn_global_load_lds((__attribute__((address_space(1))) const void*)(gp), \
                                   (__attribute__((address_space(3))) void*)(lp), 16, 0, 0)

__device__ __forceinline__ unsigned short f2bf(float x) {
  unsigned u = __builtin_bit_cast(unsigned, x);
  return (unsigned short)((u + 0x7FFFu + ((u >> 16) & 1u)) >> 16);
}
__device__ __forceinline__ float bf2f(unsigned short h) {
  unsigned u = ((unsigned)h) << 16;
  return __builtin_bit_cast(float, u);
}

// ---------------------------------------------------------------------------
// fp32 -> planar (hi, lo) bf16 split, 8 elem/thread.
// ---------------------------------------------------------------------------
__global__ __launch_bounds__(256)
void k_split(const float* __restrict__ x, short* __restrict__ h,
             short* __restrict__ l, int n8)
{
  const int i = blockIdx.x * 256 + threadIdx.x;
  if (i >= n8) return;
  float4 a = ((const float4*)x)[2 * i];
  float4 b = ((const float4*)x)[2 * i + 1];
  float v[8] = {a.x, a.y, a.z, a.w, b.x, b.y, b.z, b.w};
  short8 hh, ll;
#pragma unroll
  for (int e = 0; e < 8; ++e) {
    unsigned short hi = f2bf(v[e]);
    hh[e] = (short)hi;
    ll[e] = (short)f2bf(v[e] - bf2f(hi));
  }
  ((short8*)h)[i] = hh;
  ((short8*)l)[i] = ll;
}

// ---------------------------------------------------------------------------
// C[M x Ndim] = (AH+AL) * (WH+WL)^T, 3-term. 128x128 tile, BK=32, 256 thr.
// LDS rows: 64 shorts = [32 H | 32 L], XOR-swizzled in 16B slots.
// EPI=0: route qkv -> qk planar [8192][1536] + vT planar [96][64][1024].
// EPI=1: fp32 + bias.
// ---------------------------------------------------------------------------
template <int EPI>
__global__ __launch_bounds__(256, 3)
void k_gemm(const short* __restrict__ AH, const short* __restrict__ AL,
            const short* __restrict__ WH, const short* __restrict__ WL,
            const float* __restrict__ bias, float* __restrict__ Cf,
            short* __restrict__ qkH, short* __restrict__ qkL,
            short* __restrict__ vTH, short* __restrict__ vTL,
            int Ndim, int K)
{
  __shared__ __align__(16) short As[128 * 64];   // 16 KiB
  __shared__ __align__(16) short Ws[128 * 64];   // 16 KiB

  const int tid = threadIdx.x, lane = tid & 63, w = tid >> 6;
  const int wm = w >> 1, wn = w & 1;
  const int fr = lane & 15, g = lane >> 4;
  const int bm = blockIdx.x * 128, bn = blockIdx.y * 128;

  const int l3 = lane >> 3;            // 0..7
  const int ssrc = (lane & 7) ^ l3;    // source slot for linear-dest swizzle

  const f32x4 zero4 = {0.f, 0.f, 0.f, 0.f};
  f32x4 acc[4][4];
#pragma unroll
  for (int i = 0; i < 4; ++i)
#pragma unroll
    for (int j = 0; j < 4; ++j) acc[i][j] = zero4;

  const short* aplane = (ssrc < 4) ? AH : AL;
  const short* wplane = (ssrc < 4) ? WH : WL;
  const int scol = (ssrc & 3) * 8;

  const int nk = K >> 5;
  for (int kt = 0; kt < nk; ++kt) {
    const int k0 = kt << 5;
    __syncthreads();
#pragma unroll
    for (int c = 0; c < 8; ++c) {
      const int gidx = w * 8 + c;
      const int ch = gidx & 15;
      const int row = ch * 8 + l3;
      if (gidx < 16) {
        GLDS16(aplane + (size_t)(bm + row) * K + k0 + scol, &As[ch * 512]);
      } else {
        GLDS16(wplane + (size_t)(bn + row) * K + k0 + scol, &Ws[ch * 512]);
      }
    }
    __syncthreads();

    short8 aH[4], aL[4], bH[4], bL[4];
#pragma unroll
    for (int i = 0; i < 4; ++i) {
      const int ra = wm * 64 + i * 16 + fr;
      aH[i] = *(const short8*)&As[ra * 64 + ((g ^ (ra & 7)) * 8)];
      aL[i] = *(const short8*)&As[ra * 64 + (((4 + g) ^ (ra & 7)) * 8)];
      const int rb = wn * 64 + i * 16 + fr;
      bH[i] = *(const short8*)&Ws[rb * 64 + ((g ^ (rb & 7)) * 8)];
      bL[i] = *(const short8*)&Ws[rb * 64 + (((4 + g) ^ (rb & 7)) * 8)];
    }
#pragma unroll
    for (int i = 0; i < 4; ++i)
#pragma unroll
      for (int j = 0; j < 4; ++j) {
        acc[i][j] = MFMA(aH[i], bH[j], acc[i][j]);
        acc[i][j] = MFMA(aH[i], bL[j], acc[i][j]);
        acc[i][j] = MFMA(aL[i], bH[j], acc[i][j]);
      }
  }

  // ---- epilogue (D-layout: col=lane&15, row=(lane>>4)*4+r) ----
  const int row0 = bm + wm * 64 + g * 4;
  if constexpr (EPI == 0) {
    const int colbase = bn + wn * 64;           // 64-aligned, single species
    const int species = (colbase >> 6) % 3;     // 0:q 1:k 2:v
    const int head = colbase / 192;
    if (species < 2) {
      const int qkcol0 = head * 128 + species * 64 + fr;
#pragma unroll
      for (int i = 0; i < 4; ++i)
#pragma unroll
        for (int j = 0; j < 4; ++j) {
          const size_t base = (size_t)(row0 + i * 16) * 1536 + qkcol0 + j * 16;
#pragma unroll
          for (int r = 0; r < 4; ++r) {
            const float x = acc[i][j][r];
            const unsigned short hi = f2bf(x);
            qkH[base + (size_t)r * 1536] = (short)hi;
            qkL[base + (size_t)r * 1536] = (short)f2bf(x - bf2f(hi));
          }
        }
    } else {
#pragma unroll
      for (int i = 0; i < 4; ++i) {
        const int n0 = row0 + i * 16;
        const int b = n0 >> 10, n = n0 & 1023;
#pragma unroll
        for (int j = 0; j < 4; ++j) {
          const int dv = j * 16 + fr;
          short4 h4, l4;
#pragma unroll
          for (int r = 0; r < 4; ++r) {
            const float x = acc[i][j][r];
            const unsigned short hi = f2bf(x);
            ((short*)&h4)[r] = (short)hi;
            ((short*)&l4)[r] = (short)f2bf(x - bf2f(hi));
          }
          const size_t vidx = ((size_t)(b * 12 + head) * 64 + dv) * 1024 + n;
          *(short4*)&vTH[vidx] = h4;
          *(short4*)&vTL[vidx] = l4;
        }
      }
    }
  } else {
    const int col0 = bn + wn * 64 + fr;
    float bj[4];
#pragma unroll
    for (int j = 0; j < 4; ++j) bj[j] = bias[col0 + j * 16];
#pragma unroll
    for (int i = 0; i < 4; ++i)
#pragma unroll
      for (int j = 0; j < 4; ++j) {
        const int row = row0 + i * 16, col = col0 + j * 16;
#pragma unroll
        for (int r = 0; r < 4; ++r)
          Cf[(size_t)(row + r) * Ndim + col] = acc[i][j][r] + bj[j];
      }
  }
}

// ---------------------------------------------------------------------------
// Flash attention. 256 thr = 4 waves x 32 q-rows (q-tile 128), KV tiles 64.
// K,V staged via global_load_lds (swizzled source); V pre-transposed in global.
// QK 3-term, PV 2-term; row-sum via ones-MFMA. scores = 8*(q.k).
// LDS 51200 B -> 3 blocks/CU; grid 768 = one full round.
// ---------------------------------------------------------------------------
__global__ __launch_bounds__(256, 3)
void k_attn(const short* __restrict__ qkH, const short* __restrict__ qkL,
            const short* __restrict__ vTH, const short* __restrict__ vTL,
            short* __restrict__ attH, short* __restrict__ attL)
{
  __shared__ __align__(16) short Kls[2][64 * 64];  // [H/L][kv][d-slots] 16 KiB
  __shared__ __align__(16) short Vls[2][64 * 64];  // [H/L][d][kv-slots] 16 KiB
  __shared__ __align__(16) short Ps[4][32][72];    // 18 KiB

  const int tid = threadIdx.x, lane = tid & 63, w = tid >> 6;
  const int fr = lane & 15, g = lane >> 4;
  const int l3 = lane >> 3;
  const int ssrc = (lane & 7) ^ l3;

  // XCD swizzle: each XCD (bid&7) owns one batch's heads
  const int bid = blockIdx.x;
  const int lg = (bid & 7) * 96 + (bid >> 3);
  const int qt = lg & 7;          // 0..7
  const int bh = lg >> 3;         // 0..95
  const int b = bh / 12, h = bh - b * 12;

  const f32x4 zero4 = {0.f, 0.f, 0.f, 0.f};

  // Q fragments (held across all KV tiles)
  short8 qH[2][2], qL[2][2];   // [i][ks]
#pragma unroll
  for (int i = 0; i < 2; ++i) {
    const int row = qt * 128 + w * 32 + i * 16 + fr;
    const size_t base = (size_t)(b * 1024 + row) * 1536 + h * 128 + g * 8;
#pragma unroll
    for (int ks = 0; ks < 2; ++ks) {
      qH[i][ks] = *(const short8*)&qkH[base + ks * 32];
      qL[i][ks] = *(const short8*)&qkL[base + ks * 32];
    }
  }

  f32x4 O[2][4];
  float mrun[2][4], lrun[2][4];
#pragma unroll
  for (int i = 0; i < 2; ++i)
#pragma unroll
    for (int r = 0; r < 4; ++r) { mrun[i][r] = -INFINITY; lrun[i][r] = 0.f; }
#pragma unroll
  for (int i = 0; i < 2; ++i)
#pragma unroll
    for (int nf = 0; nf < 4; ++nf) O[i][nf] = zero4;

  short8 ones;
#pragma unroll
  for (int e = 0; e < 8; ++e) ones[e] = (short)0x3F80;

  // staging sources (wave w stages array w: 0=KH 1=KL 2=VH 3=VL)
  const short* kplane = (w & 1) ? qkL : qkH;
  const short* vplane = (w & 1) ? vTL : vTH;
  short* dstA = (w < 2) ? &Kls[w & 1][0] : &Vls[w & 1][0];

  for (int kt = 0; kt < 16; ++kt) {
    const int kv0 = kt * 64;
    __syncthreads();
#pragma unroll
    for (int c = 0; c < 8; ++c) {
      const int row = c * 8 + l3;
      const short* src = (w < 2)
        ? kplane + (size_t)(b * 1024 + kv0 + row) * 1536 + h * 128 + 64 + ssrc * 8
        : vplane + ((size_t)bh * 64 + row) * 1024 + kv0 + ssrc * 8;
      GLDS16(src, dstA + c * 512);
    }
    __syncthreads();

    // ---- S = Q K^T (3-term); scores = 8*S ----
    f32x4 S[2][4];
#pragma unroll
    for (int i = 0; i < 2; ++i)
#pragma unroll
      for (int nf = 0; nf < 4; ++nf) S[i][nf] = zero4;
#pragma unroll
    for (int nf = 0; nf < 4; ++nf) {
      const int rk = nf * 16 + fr;
#pragma unroll
      for (int ks = 0; ks < 2; ++ks) {
        const int t = g + 4 * ks;
        const int sidx = rk * 64 + ((t ^ (rk & 7)) * 8);
        short8 kbh = *(const short8*)&Kls[0][sidx];
        short8 kbl = *(const short8*)&Kls[1][sidx];
#pragma unroll
        for (int i = 0; i < 2; ++i) {
          S[i][nf] = MFMA(qH[i][ks], kbh, S[i][nf]);
          S[i][nf] = MFMA(qH[i][ks], kbl, S[i][nf]);
          S[i][nf] = MFMA(qL[i][ks], kbh, S[i][nf]);
        }
      }
    }

    // ---- online softmax (rows: q = w*32 + i*16 + g*4 + r) ----
    float al[2][4];
#pragma unroll
    for (int i = 0; i < 2; ++i) {
      float tl[4];
#pragma unroll
      for (int r = 0; r < 4; ++r)
        tl[r] = fmaxf(fmaxf(S[i][0][r], S[i][1][r]), fmaxf(S[i][2][r], S[i][3][r]));
#pragma unroll
      for (int off = 1; off < 16; off <<= 1)
#pragma unroll
        for (int r = 0; r < 4; ++r) tl[r] = fmaxf(tl[r], __shfl_xor(tl[r], off));
#pragma unroll
      for (int r = 0; r < 4; ++r) {
        const float mn = fmaxf(mrun[i][r], tl[r] * 8.f);   // score units
        al[i][r] = __expf(mrun[i][r] - mn);
        mrun[i][r] = mn;
#pragma unroll
        for (int nf = 0; nf < 4; ++nf) {
          const float p = __expf(fmaf(S[i][nf][r], 8.f, -mn));
          Ps[w][i * 16 + g * 4 + r][nf * 16 + fr] = (short)f2bf(p);
        }
      }
    }

    // ---- P fragments + row-sum via ones-MFMA ----
    short8 pa[2][2];
#pragma unroll
    for (int i = 0; i < 2; ++i)
#pragma unroll
      for (int ks = 0; ks < 2; ++ks)
        pa[i][ks] = *(const short8*)&Ps[w][i * 16 + fr][ks * 32 + g * 8];

#pragma unroll
    for (int i = 0; i < 2; ++i) {
      f32x4 rs = MFMA(pa[i][0], ones, zero4);
      rs = MFMA(pa[i][1], ones, rs);
#pragma unroll
      for (int r = 0; r < 4; ++r)
        lrun[i][r] = lrun[i][r] * al[i][r] + rs[r];
#pragma unroll
      for (int nf = 0; nf < 4; ++nf)
#pragma unroll
        for (int r = 0; r < 4; ++r) O[i][nf][r] *= al[i][r];
    }

    // ---- O += P V (2-term) ----
#pragma unroll
    for (int nf = 0; nf < 4; ++nf) {
      const int rd = nf * 16 + fr;
#pragma unroll
      for (int ks = 0; ks < 2; ++ks) {
        const int t = g + 4 * ks;
        const int sidx = rd * 64 + ((t ^ (rd & 7)) * 8);
        short8 vbh = *(const short8*)&Vls[0][sidx];
        short8 vbl = *(const short8*)&Vls[1][sidx];
#pragma unroll
        for (int i = 0; i < 2; ++i) {
          O[i][nf] = MFMA(pa[i][ks], vbh, O[i][nf]);
          O[i][nf] = MFMA(pa[i][ks], vbl, O[i][nf]);
        }
      }
    }
  }

  // ---- normalize + planar H/L store, merged heads [8192][768] ----
#pragma unroll
  for (int i = 0; i < 2; ++i) {
    const size_t rowbase = (size_t)(b * 1024 + qt * 128 + w * 32 + i * 16 + g * 4);
#pragma unroll
    for (int r = 0; r < 4; ++r) {
      const float inv = 1.f / lrun[i][r];
#pragma unroll
      for (int nf = 0; nf < 4; ++nf) {
        const float v = O[i][nf][r] * inv;
        const size_t idx = (rowbase + r) * 768 + h * 64 + nf * 16 + fr;
        const unsigned short hi = f2bf(v);
        attH[idx] = (short)hi;
        attL[idx] = (short)f2bf(v - bf2f(hi));
      }
    }
  }
}

// ---------------------------------------------------------------------------

extern "C" void kernel_launch(void* const* d_in, const int* in_sizes, int n_in,
                              void* d_out, int out_size, void* d_ws, size_t ws_size,
                              hipStream_t stream)
{
  const float* img  = (const float*)d_in[0];   // [8,1024,768]
  const float* Wqkv = (const float*)d_in[1];   // [2304,768]
  const float* Wfc  = (const float*)d_in[2];   // [768,768]
  const float* bfc  = (const float*)d_in[3];   // [768]
  float* outp = (float*)d_out;                 // [8,1024,768] fp32

  char* ws = (char*)d_ws;
  short* qkH   = (short*)(ws);                  //  0        .. 25165824
  short* qkL   = (short*)(ws + 25165824);       // 25.2 MB
  short* vTH   = (short*)(ws + 50331648);       // 12.6 MB
  short* vTL   = (short*)(ws + 62914560);
  short* imgH  = (short*)(ws + 75497472);       // 12.6 MB (aliased attH)
  short* imgL  = (short*)(ws + 88080384);       // 12.6 MB (aliased attL)
  short* WqkvH = (short*)(ws + 100663296);
  short* WqkvL = (short*)(ws + 104202240);
  short* WfcH  = (short*)(ws + 107741184);
  short* WfcL  = (short*)(ws + 108920832);      // end 110,100,480
  short* attH  = imgH;
  short* attL  = imgL;

  // 0) fp32 -> planar hi/lo bf16
  k_split<<<3072, 256, 0, stream>>>(img,  imgH,  imgL,  786432);
  k_split<<<864,  256, 0, stream>>>(Wqkv, WqkvH, WqkvL, 221184);
  k_split<<<288,  256, 0, stream>>>(Wfc,  WfcH,  WfcL,  73728);
  // 1) qkv = img @ Wqkv^T  -> qk planar + vT planar
  k_gemm<0><<<dim3(64, 18), dim3(256), 0, stream>>>(
      imgH, imgL, WqkvH, WqkvL, nullptr, nullptr,
      qkH, qkL, vTH, vTL, 2304, 768);
  // 2) flash attention -> att planar
  k_attn<<<dim3(768), dim3(256), 0, stream>>>(qkH, qkL, vTH, vTL, attH, attL);
  // 3) out = att @ Wfc^T + b  (fp32)
  k_gemm<1><<<dim3(64, 6), dim3(256), 0, stream>>>(
      attH, attL, WfcH, WfcL, bfc, outp,
      nullptr, nullptr, nullptr, nullptr, 768, 768);
}